// Round 1
// baseline (970.234 us; speedup 1.0000x reference)
//
#include <hip/hip_runtime.h>

// Problem constants
// T=2048 tokens, H=1024 hidden, E=32 experts, I=2048 (ffn), top-2 routing.
#define T_TOK   2048
#define H_DIM   1024
#define N_EXP   32
#define I_DIM   2048
#define I2_DIM  4096
#define MAXROWS (4096 + 256)   // 2*T assignments + BM slack
#define MAXTILES 48            // sum_e ceil(ne/256) <= 31 + 16 = 47

typedef __attribute__((ext_vector_type(8))) short bf16x8;
typedef __attribute__((ext_vector_type(4))) float f32x4;

__device__ __forceinline__ unsigned short f2bf(float f) {
    unsigned u = __float_as_uint(f);
    unsigned r = (u + 0x7FFFu + ((u >> 16) & 1u)) >> 16;  // RNE
    return (unsigned short)r;
}
__device__ __forceinline__ unsigned pack2(float a, float b) {
    return (unsigned)f2bf(a) | ((unsigned)f2bf(b) << 16);
}

// Async global->LDS, 16 bytes/lane. LDS dest is wave-uniform base + lane*16;
// global source is per-lane (m173 pattern: swizzle the SOURCE, keep LDS linear).
__device__ __forceinline__ void gload_lds16(const void* g, void* l) {
    __builtin_amdgcn_global_load_lds(
        (const __attribute__((address_space(1))) unsigned int*)g,
        (__attribute__((address_space(3))) unsigned int*)l,
        16, 0, 0);
}

// ---------------------------------------------------------------- router ----
// Per block: 8 tokens. mix = x @ wqkv^T (fp32), attention over experts,
// top-2 + softmax, append to per-expert lists via atomics. (unchanged, verified)
__global__ __launch_bounds__(256) void router_kernel(
    const float* __restrict__ x, const float* __restrict__ wqkv,
    int* __restrict__ counts, int* __restrict__ tok_e,
    int* __restrict__ tok_slot, float* __restrict__ tok_w)
{
    __shared__ float xs[8][1024];
    __shared__ float mixs[8][96];
    __shared__ float lg[8][32];
    const int tid = threadIdx.x;
    const int t0  = blockIdx.x * 8;

    const float4* src = (const float4*)(x + (size_t)t0 * H_DIM);
    float4* dst = (float4*)&xs[0][0];
#pragma unroll
    for (int i = 0; i < 8; ++i) dst[i * 256 + tid] = src[i * 256 + tid];
    __syncthreads();

    const int j  = tid & 127;
    const int th = tid >> 7;
    if (j < 96) {
        float a0 = 0.f, a1 = 0.f, a2 = 0.f, a3 = 0.f;
        const float* wr = wqkv + (size_t)j * H_DIM;
        for (int k = 0; k < H_DIM; k += 4) {
            float4 wv = *(const float4*)(wr + k);
            float4 x0 = *(const float4*)&xs[th * 4 + 0][k];
            float4 x1 = *(const float4*)&xs[th * 4 + 1][k];
            float4 x2 = *(const float4*)&xs[th * 4 + 2][k];
            float4 x3 = *(const float4*)&xs[th * 4 + 3][k];
            a0 += wv.x * x0.x + wv.y * x0.y + wv.z * x0.z + wv.w * x0.w;
            a1 += wv.x * x1.x + wv.y * x1.y + wv.z * x1.z + wv.w * x1.w;
            a2 += wv.x * x2.x + wv.y * x2.y + wv.z * x2.z + wv.w * x2.w;
            a3 += wv.x * x3.x + wv.y * x3.y + wv.z * x3.z + wv.w * x3.w;
        }
        mixs[th * 4 + 0][j] = a0;
        mixs[th * 4 + 1][j] = a1;
        mixs[th * 4 + 2][j] = a2;
        mixs[th * 4 + 3][j] = a3;
    }
    __syncthreads();

    {   // attention over experts: logit[e] = sum_f softmax_f(q_e*k_f) * v_f
        const int tt = tid >> 5, e2 = tid & 31;
        const float q = mixs[tt][e2];
        float mmax = -3.4e38f;
        for (int f = 0; f < 32; ++f) mmax = fmaxf(mmax, q * mixs[tt][32 + f]);
        float s = 0.f, num = 0.f;
        for (int f = 0; f < 32; ++f) {
            float p = expf(q * mixs[tt][32 + f] - mmax);
            s += p;
            num += p * mixs[tt][64 + f];
        }
        lg[tt][e2] = num / s;
    }
    __syncthreads();

    if (tid < 8) {   // top-2 (stable: strict >, lower index wins ties) + softmax
        const int t = t0 + tid;
        float b0 = -3.4e38f, b1 = -3.4e38f;
        int i0 = 0, i1 = 0;
        for (int e2 = 0; e2 < 32; ++e2) {
            float l = lg[tid][e2];
            if (l > b0)      { b1 = b0; i1 = i0; b0 = l; i0 = e2; }
            else if (l > b1) { b1 = l; i1 = e2; }
        }
        float e1 = expf(b1 - b0);
        float w0 = 1.f / (1.f + e1);
        float w1 = e1 / (1.f + e1);
        int p = t * 2;
        int s0 = atomicAdd(&counts[i0], 1);
        int s1 = atomicAdd(&counts[i1], 1);
        tok_e[p] = i0;     tok_slot[p] = s0;     tok_w[p] = w0;
        tok_e[p + 1] = i1; tok_slot[p + 1] = s1; tok_w[p + 1] = w1;
    }
}

// ------------------------------------------------------------------ scan ----
// Prefix-sum of counts + build a flattened (expert, row-tile) work table so
// GEMM blocks are load-balanced under expert skew.
__global__ void scan_kernel(const int* __restrict__ counts, int* __restrict__ offsets,
                            int* __restrict__ tile_e, int* __restrict__ tile_r0,
                            int* __restrict__ n_tiles)
{
    if (threadIdx.x == 0) {
        int run = 0, nt = 0;
        for (int e = 0; e < N_EXP; ++e) {
            offsets[e] = run;
            for (int r0 = 0; r0 < counts[e]; r0 += 256) {
                tile_e[nt] = e; tile_r0[nt] = r0; ++nt;
            }
            run += counts[e];
        }
        *n_tiles = nt;
    }
}

// ---------------------------------------------------------------- gather ----
__global__ __launch_bounds__(128) void gather_kernel(
    const float* __restrict__ x, const int* __restrict__ tok_e,
    const int* __restrict__ tok_slot, const int* __restrict__ offsets,
    unsigned short* __restrict__ xg, int* __restrict__ rowof)
{
    const int p = blockIdx.x;
    const int t = p >> 1;
    const int e = tok_e[p];
    const int row = offsets[e] + tok_slot[p];
    if (threadIdx.x == 0) rowof[p] = row;
    const int k = threadIdx.x * 8;
    const float4* s = (const float4*)(x + (size_t)t * H_DIM + k);
    float4 f0 = s[0], f1 = s[1];
    uint4 v;
    v.x = pack2(f0.x, f0.y); v.y = pack2(f0.z, f0.w);
    v.z = pack2(f1.x, f1.y); v.w = pack2(f1.z, f1.w);
    *(uint4*)(xg + (size_t)row * H_DIM + k) = v;
}

// ----------------------------------------------------------------- GEMM1 ----
// act[row, 0:2048] = silu(x@Wg^T) * (x@Wu^T), per expert.
// One block per (work-table tile, 64 act-cols). BK=64.
// A-tile: linear LDS [256][64], staged via global_load_lds w/ XOR-swizzled
// per-lane SOURCE column (chunk' = chunk ^ (row&7)); read applies same XOR.
__global__ __launch_bounds__(256, 2) void gemm1_kernel(
    const unsigned short* __restrict__ xg,   // bf16 [MAXROWS][1024]
    const float* __restrict__ w13,           // [E][4096][1024]
    const int* __restrict__ counts, const int* __restrict__ offsets,
    const int* __restrict__ tile_e, const int* __restrict__ tile_r0,
    const int* __restrict__ n_tiles,
    unsigned short* __restrict__ act)        // bf16 [MAXROWS][2048]
{
    const int ti = blockIdx.y;
    if (ti >= *n_tiles) return;
    const int e    = tile_e[ti];
    const int row0 = tile_r0[ti];
    const int ne   = counts[e];
    const int ro   = offsets[e];
    const int gc   = blockIdx.x * 64;
    const long grow0 = (long)ro + row0;

    __shared__ unsigned short As[256][64];  // 32 KB, linear (chunk-swizzled content)
    __shared__ unsigned short Bs[128][72];  // 18 KB padded (verified layout)

    const int tid  = threadIdx.x;
    const int wave = tid >> 6;
    const int lane = tid & 63;
    const int m    = lane & 15;
    const int quad = lane >> 4;
    const int ar   = tid >> 3;    // row within a 32-row staging slab
    const int ac   = tid & 7;     // dest 16B-chunk within row (== lane&7)
    const float* wbase = w13 + (size_t)e * ((size_t)I2_DIM * H_DIM);
    // wave-level tail skip: whole 64-row slab out of range -> no MFMA
    const bool wactive = (row0 + wave * 64) < ne;

    f32x4 acc[4][8];
#pragma unroll
    for (int a = 0; a < 4; ++a)
#pragma unroll
        for (int b = 0; b < 8; ++b) acc[a][b] = (f32x4)0.f;

    for (int ks = 0; ks < H_DIM; ks += 64) {
        // stage A: async DMA, 8x16B per thread; source column pre-swizzled
#pragma unroll
        for (int i = 0; i < 8; ++i) {
            const int r  = i * 32 + ar;            // 0..255
            const int cs = ac ^ (r & 7);           // source chunk for this dest slot
            gload_lds16(xg + (grow0 + r) * (size_t)H_DIM + ks + cs * 8,
                        &As[0][0] + (i * 256 + wave * 64) * 8);
        }
        // stage B: 128 weight rows (64 gate + 64 up) x 64 k, fp32 -> bf16
#pragma unroll
        for (int i = 0; i < 4; ++i) {
            int g = i * 256 + tid;
            int r = g >> 3, kg = g & 7;
            int wr = (r < 64) ? (gc + r) : (2048 + gc + (r - 64));
            const float* sp = wbase + (size_t)wr * H_DIM + ks + kg * 8;
            float4 f0 = *(const float4*)sp;
            float4 f1 = *(const float4*)(sp + 4);
            uint4 v;
            v.x = pack2(f0.x, f0.y); v.y = pack2(f0.z, f0.w);
            v.z = pack2(f1.x, f1.y); v.w = pack2(f1.z, f1.w);
            *(uint4*)&Bs[r][kg * 8] = v;
        }
        __syncthreads();   // drains vmcnt (gload_lds) + lgkmcnt (ds_write)
        if (wactive) {
#pragma unroll
            for (int kc = 0; kc < 2; ++kc) {
                bf16x8 a[4];
#pragma unroll
                for (int mt = 0; mt < 4; ++mt) {
                    const int R = wave * 64 + mt * 16 + m;
                    a[mt] = *(const bf16x8*)&As[R][((kc * 4 + quad) ^ (R & 7)) * 8];
                }
#pragma unroll
                for (int ct = 0; ct < 8; ++ct) {
                    int br = (ct < 4) ? (ct * 16 + m) : (64 + (ct - 4) * 16 + m);
                    bf16x8 b = *(const bf16x8*)&Bs[br][kc * 32 + quad * 8];
#pragma unroll
                    for (int mt = 0; mt < 4; ++mt)
                        acc[mt][ct] = __builtin_amdgcn_mfma_f32_16x16x32_bf16(
                            a[mt], b, acc[mt][ct], 0, 0, 0);
                }
            }
        }
        __syncthreads();
    }
    // epilogue: silu(gate)*up -> bf16, stage in As (linear, no swizzle), store
#pragma unroll
    for (int mt = 0; mt < 4; ++mt)
#pragma unroll
        for (int ct = 0; ct < 4; ++ct)
#pragma unroll
            for (int rg = 0; rg < 4; ++rg) {
                int r   = wave * 64 + mt * 16 + quad * 4 + rg;
                int col = ct * 16 + m;
                float g = acc[mt][ct][rg];
                float u = acc[mt][ct + 4][rg];
                float s = g / (1.f + __expf(-g)) * u;
                As[r][col] = f2bf(s);
            }
    __syncthreads();
#pragma unroll
    for (int i = 0; i < 8; ++i) {
        int g = i * 256 + tid;
        int r = g >> 3, kg = g & 7;
        if (row0 + r < ne)
            *(uint4*)(act + (grow0 + r) * (long)I_DIM + gc + kg * 8) =
                *(const uint4*)&As[r][kg * 8];
    }
}

// ----------------------------------------------------------------- GEMM2 ----
// part[row, 0:1024] = act[row] @ w2[e]^T. One block per (tile, 64 h-cols). BK=64.
__global__ __launch_bounds__(256, 3) void gemm2_kernel(
    const unsigned short* __restrict__ act,  // bf16 [MAXROWS][2048]
    const float* __restrict__ w2,            // [E][1024][2048]
    const int* __restrict__ counts, const int* __restrict__ offsets,
    const int* __restrict__ tile_e, const int* __restrict__ tile_r0,
    const int* __restrict__ n_tiles,
    float* __restrict__ part)                // fp32 [MAXROWS][1024]
{
    const int ti = blockIdx.y;
    if (ti >= *n_tiles) return;
    const int e    = tile_e[ti];
    const int row0 = tile_r0[ti];
    const int ne   = counts[e];
    const int ro   = offsets[e];
    const int hc   = blockIdx.x * 64;
    const long grow0 = (long)ro + row0;

    __shared__ unsigned short As[256][64];  // 32 KB linear, chunk-swizzled
    __shared__ unsigned short Bs[64][72];   //  9 KB

    const int tid  = threadIdx.x;
    const int wave = tid >> 6;
    const int lane = tid & 63;
    const int m    = lane & 15;
    const int quad = lane >> 4;
    const int ar   = tid >> 3;
    const int ac   = tid & 7;
    const float* wbase = w2 + (size_t)e * ((size_t)1024 * I_DIM);
    const bool wactive = (row0 + wave * 64) < ne;

    f32x4 acc[4][4];
#pragma unroll
    for (int a = 0; a < 4; ++a)
#pragma unroll
        for (int b = 0; b < 4; ++b) acc[a][b] = (f32x4)0.f;

    for (int ks = 0; ks < I_DIM; ks += 64) {
#pragma unroll
        for (int i = 0; i < 8; ++i) {
            const int r  = i * 32 + ar;
            const int cs = ac ^ (r & 7);
            gload_lds16(act + (grow0 + r) * (size_t)I_DIM + ks + cs * 8,
                        &As[0][0] + (i * 256 + wave * 64) * 8);
        }
#pragma unroll
        for (int i = 0; i < 2; ++i) {
            int g = i * 256 + tid;
            int r = g >> 3, kg = g & 7;
            const float* sp = wbase + (size_t)(hc + r) * I_DIM + ks + kg * 8;
            float4 f0 = *(const float4*)sp;
            float4 f1 = *(const float4*)(sp + 4);
            uint4 v;
            v.x = pack2(f0.x, f0.y); v.y = pack2(f0.z, f0.w);
            v.z = pack2(f1.x, f1.y); v.w = pack2(f1.z, f1.w);
            *(uint4*)&Bs[r][kg * 8] = v;
        }
        __syncthreads();
        if (wactive) {
#pragma unroll
            for (int kc = 0; kc < 2; ++kc) {
                bf16x8 a[4];
#pragma unroll
                for (int mt = 0; mt < 4; ++mt) {
                    const int R = wave * 64 + mt * 16 + m;
                    a[mt] = *(const bf16x8*)&As[R][((kc * 4 + quad) ^ (R & 7)) * 8];
                }
#pragma unroll
                for (int ct = 0; ct < 4; ++ct) {
                    bf16x8 b = *(const bf16x8*)&Bs[ct * 16 + m][kc * 32 + quad * 8];
#pragma unroll
                    for (int mt = 0; mt < 4; ++mt)
                        acc[mt][ct] = __builtin_amdgcn_mfma_f32_16x16x32_bf16(
                            a[mt], b, acc[mt][ct], 0, 0, 0);
                }
            }
        }
        __syncthreads();
    }
    // epilogue: direct fp32 stores (lanes 0..15 contiguous -> 64B segments)
#pragma unroll
    for (int mt = 0; mt < 4; ++mt)
#pragma unroll
        for (int ct = 0; ct < 4; ++ct)
#pragma unroll
            for (int rg = 0; rg < 4; ++rg) {
                int r = wave * 64 + mt * 16 + quad * 4 + rg;
                if (row0 + r < ne)
                    part[(grow0 + r) * (long)1024 + hc + ct * 16 + m] = acc[mt][ct][rg];
            }
}

// --------------------------------------------------------------- combine ----
__global__ __launch_bounds__(256) void combine_kernel(
    const float* __restrict__ part, const int* __restrict__ rowof,
    const float* __restrict__ tok_w, float* __restrict__ out)
{
    const int t = blockIdx.x;
    const int r0 = rowof[2 * t], r1 = rowof[2 * t + 1];
    const float w0 = tok_w[2 * t], w1 = tok_w[2 * t + 1];
    const int k = threadIdx.x * 4;
    float4 p0 = *(const float4*)(part + (size_t)r0 * 1024 + k);
    float4 p1 = *(const float4*)(part + (size_t)r1 * 1024 + k);
    float4 o;
    o.x = w0 * p0.x + w1 * p1.x;
    o.y = w0 * p0.y + w1 * p1.y;
    o.z = w0 * p0.z + w1 * p1.z;
    o.w = w0 * p0.w + w1 * p1.w;
    *(float4*)(out + (size_t)t * 1024 + k) = o;
}

// ---------------------------------------------------------------- launch ----
extern "C" void kernel_launch(void* const* d_in, const int* in_sizes, int n_in,
                              void* d_out, int out_size, void* d_ws, size_t ws_size,
                              hipStream_t stream)
{
    (void)in_sizes; (void)n_in; (void)out_size; (void)ws_size;
    const float* x    = (const float*)d_in[0];
    const float* wqkv = (const float*)d_in[1];
    const float* w13  = (const float*)d_in[2];
    const float* w2   = (const float*)d_in[3];
    float* out = (float*)d_out;

    char* ws = (char*)d_ws;
    int*   counts   = (int*)(ws + 0);          // 32 ints (memset to 0)
    int*   offsets  = (int*)(ws + 256);        // 32 ints
    int*   tok_e    = (int*)(ws + 1024);       // 4096 ints
    int*   tok_slot = (int*)(ws + 17408);      // 4096 ints
    float* tok_w    = (float*)(ws + 33792);    // 4096 floats
    int*   rowof    = (int*)(ws + 50176);      // 4096 ints
    int*   tile_e   = (int*)(ws + 66560);      // 48 ints
    int*   tile_r0  = (int*)(ws + 66816);      // 48 ints
    int*   n_tiles  = (int*)(ws + 67072);      // 1 int
    unsigned short* xg  = (unsigned short*)(ws + (1u  << 20)); // bf16 [4352][1024]  8.9 MB
    unsigned short* act = (unsigned short*)(ws + (16u << 20)); // bf16 [4352][2048] 17.8 MB
    float*          part= (float*)(ws + (40u << 20));          // fp32 [4352][1024] 17.8 MB

    hipMemsetAsync(counts, 0, 256, stream);
    hipLaunchKernelGGL(router_kernel, dim3(T_TOK / 8), dim3(256), 0, stream,
                       x, wqkv, counts, tok_e, tok_slot, tok_w);
    hipLaunchKernelGGL(scan_kernel, dim3(1), dim3(64), 0, stream,
                       counts, offsets, tile_e, tile_r0, n_tiles);
    hipLaunchKernelGGL(gather_kernel, dim3(2 * T_TOK), dim3(128), 0, stream,
                       x, tok_e, tok_slot, offsets, xg, rowof);
    hipLaunchKernelGGL(gemm1_kernel, dim3(I_DIM / 64, MAXTILES), dim3(256), 0, stream,
                       xg, w13, counts, offsets, tile_e, tile_r0, n_tiles, act);
    hipLaunchKernelGGL(gemm2_kernel, dim3(1024 / 64, MAXTILES), dim3(256), 0, stream,
                       act, w2, counts, offsets, tile_e, tile_r0, n_tiles, part);
    hipLaunchKernelGGL(combine_kernel, dim3(T_TOK), dim3(256), 0, stream,
                       part, rowof, tok_w, out);
}